// Round 12
// baseline (146.802 us; speedup 1.0000x reference)
//
#include <hip/hip_runtime.h>
#include <hip/hip_bf16.h>
#include <hip/hip_cooperative_groups.h>

namespace cg = cooperative_groups;

typedef unsigned short u16;
typedef __attribute__((ext_vector_type(8))) short short8;
typedef __attribute__((ext_vector_type(4))) float floatx4;

#define NROWS 8192
#define DIM 256

__device__ __forceinline__ void atomicMinFloat(float* addr, float val) {
    if (val >= 0.0f) {
        atomicMin((int*)addr, __float_as_int(val));
    } else {
        atomicMax((unsigned int*)addr, __float_as_uint(val));
    }
}

__device__ __forceinline__ u16 f32_to_bf16_rne(float x) {
    unsigned int u = __float_as_uint(x);
    unsigned int r = (u + 0x7fffu + ((u >> 16) & 1u)) >> 16;
    return (u16)r;
}

// C(M) = -logp * exp(logp); quasiconcave in M => rowmin = min(C(minM), C(maxM)).
__device__ __forceinline__ float c_of_m(float m) {
    const float INV_SIG = 1.0f / 0.3f;
    const float KC = 0.28503427f;  // -ln(0.3) - 0.5*ln(2*pi)
    float z = (m - 1.0f) * INV_SIG;
    float logp = fmaf(-0.5f * z, z, KC);
    return -logp * __expf(logp);
}

// 16B async DMA global -> LDS. LDS dest is wave-uniform base + lane*16.
__device__ __forceinline__ void load16(const u16* g, u16* l) {
    __builtin_amdgcn_global_load_lds(
        (__attribute__((address_space(1))) void*)g,
        (__attribute__((address_space(3))) void*)l, 16, 0, 0);
}

// R28: FUSED cooperative kernel. R11 closed the intra-GEMM box: 6 distinct
// schedules (setprio/8-phase/free-run/16-wave/reg-headroom/rotation/32x32/
// 4-ring) all land at gemm ~= 30-33 us (m97-class ceiling; K=256 = 8
// kt-steps/ct is too shallow for the HK 8-phase schedule). Remaining
// attackable us are BETWEEN kernels: norm launch + gap + tail ~3-5 us.
// Fusion: phase 1 = normalize (identical arithmetic -> same absmax, same
// panel layouts), cg grid sync (device-scope fences), phase 2 = R8 champion
// gemm body verbatim (2-deep bfA/bfB pipeline + early-fold, measured best).
// Grid 256 x 512 (1 block/CU, co-resident -> cooperative legal).
__global__ void __launch_bounds__(512, 2)
fused_kernel(const float* __restrict__ Ex,
             const float* __restrict__ Ey,
             u16* __restrict__ Xs,
             u16* __restrict__ Ys,
             float* __restrict__ out) {
    __shared__ u16 Bs[2][16 * 512];  // 2 x 16 KB

    const int tid = threadIdx.x;
    const int w = tid >> 6;      // 0..7
    const int lane = tid & 63;

    // ---------- Phase 1: normalize 64 rows per block (8 per wave) ----------
    // Blocks 0..127 -> X rows, 128..255 -> Y rows. Wave per row, float4
    // loads; panel layout (verified R5/R11/R14/R15):
    //   (row r, k) -> flat[ ((p*8+kt)*64 + lq*16 + lm)*8 + j ]
    {
        const int gr0 = blockIdx.x * 64 + w * 8;       // first of 8 rows
        const bool isX = gr0 < NROWS;                  // block-uniform
        const float* src = isX ? Ex : Ey;
        u16* dst = isX ? Xs : Ys;
        #pragma unroll
        for (int s = 0; s < 8; ++s) {
            const int row = (gr0 + s) & (NROWS - 1);
            float4 v = *(const float4*)(src + (size_t)row * DIM + lane * 4);
            float sm = fmaf(v.x, v.x, fmaf(v.y, v.y, fmaf(v.z, v.z, v.w * v.w)));
            #pragma unroll
            for (int m = 32; m >= 1; m >>= 1) sm += __shfl_xor(sm, m, 64);
            float inv = 1.0f / fmaxf(sqrtf(sm), 1e-8f);

            ushort4 o;
            o.x = f32_to_bf16_rne(v.x * inv);
            o.y = f32_to_bf16_rne(v.y * inv);
            o.z = f32_to_bf16_rne(v.z * inv);
            o.w = f32_to_bf16_rne(v.w * inv);

            const int p = row >> 4;
            const int lmn = row & 15;
            const int ktn = lane >> 3;
            const int lqn = (lane >> 1) & 3;
            const int j4 = (lane & 1) * 4;
            const size_t off =
                ((size_t)((p * 8 + ktn) * 64 + lqn * 16 + lmn)) * 8 + j4;
            *(ushort4*)(dst + off) = o;

            if (isX && lane == 0) out[row] = __uint_as_float(0x7f800000u);
        }
    }

    cg::this_grid().sync();  // Xs/Ys globally visible; out initialized

    // ---------- Phase 2: R8 champion gemm body ----------
    const int lq = lane >> 4;
    const int lm = lane & 15;

    // XCD-aware remap (dispatch i -> XCD i&7 round-robin): XCD x gets a
    // 4 row-tile x 8 col-group region. Bijective over the 16x16 grid.
    const int i = blockIdx.x;
    const int x = i & 7;
    const int jj = i >> 3;                      // 0..31 within XCD
    const int rt = (x & 3) * 4 + (jj & 3);      // row-tile 0..15
    const int cgrp = (x >> 2) * 8 + (jj >> 2);  // col-group 0..15

    const int rowStart = rt * 512;
    const int rowPan0 = rt * 32 + w * 4;
    const u16* ybase = Ys + (size_t)cgrp * 32 * 4096;  // advances 8192 u16/ct

    // Stage one 32col x 256k B tile (16 KB = 16 x 1 KB units) via DMA.
    // 8 waves x 2 units; unit u -> (col-panel u>>3, kt u&7); LDS slot u*512
    // so fragment reads are Bs[(cg*8+kt)*512 + lane*8] (b128, conflict-free).
    auto stage1 = [&](int buf, const u16* yb, int iu) {
        const int u = w * 2 + iu;
        load16(yb + (u >> 3) * 4096 + (u & 7) * 512 + lane * 8,
               &Bs[buf][u * 512]);
    };

    short8 a[4][8];
    auto loadA = [&](int kt) {
        #pragma unroll
        for (int rg = 0; rg < 4; ++rg)
            a[rg][kt] = *(const short8*)(
                Xs + ((size_t)(rowPan0 + rg) * 8 + kt) * 512 + lane * 8);
    };

    floatx4 mn4[4], mx4[4];
    #pragma unroll
    for (int rg = 0; rg < 4; ++rg) {
        mn4[rg] = (floatx4){3.4e38f, 3.4e38f, 3.4e38f, 3.4e38f};
        mx4[rg] = (floatx4){-3.4e38f, -3.4e38f, -3.4e38f, -3.4e38f};
    }

    floatx4 acc[4][2];
    const floatx4 FZ = (floatx4){0.0f, 0.0f, 0.0f, 0.0f};

    auto fold = [&]() {
        #pragma unroll
        for (int rg = 0; rg < 4; ++rg)
            #pragma unroll
            for (int cg = 0; cg < 2; ++cg)
                #pragma unroll
                for (int r = 0; r < 4; ++r) {
                    float m = acc[rg][cg][r];
                    mn4[rg][r] = fminf(mn4[rg][r], m);
                    mx4[rg][r] = fmaxf(mx4[rg][r], m);
                }
    };

    // 2-deep bfA/bfB software pipeline (R7-measured win); dofold folds the
    // previous ct's acc inside the first reads' latency window (R8).
    auto compute = [&](int buf, int dofold) {
        const u16* bsb = &Bs[buf][0];
        short8 bfA[2], bfB[2];
        #pragma unroll
        for (int cg = 0; cg < 2; ++cg)
            bfA[cg] = *(const short8*)(bsb + (cg * 8 + 0) * 512 + lane * 8);
        #pragma unroll
        for (int cg = 0; cg < 2; ++cg)
            bfB[cg] = *(const short8*)(bsb + (cg * 8 + 1) * 512 + lane * 8);
        if (dofold) fold();
        #pragma unroll
        for (int k2 = 0; k2 < 4; ++k2) {
            const int ke = 2 * k2;      // even kt, uses bfA
            const int ko = ke + 1;      // odd kt, uses bfB
            if (ke == 0) {
                #pragma unroll
                for (int cg = 0; cg < 2; ++cg)
                    #pragma unroll
                    for (int rg = 0; rg < 4; ++rg)
                        acc[rg][cg] = __builtin_amdgcn_mfma_f32_16x16x32_bf16(
                            a[rg][0], bfA[cg], FZ, 0, 0, 0);
            } else {
                #pragma unroll
                for (int cg = 0; cg < 2; ++cg)
                    #pragma unroll
                    for (int rg = 0; rg < 4; ++rg)
                        acc[rg][cg] = __builtin_amdgcn_mfma_f32_16x16x32_bf16(
                            a[rg][ke], bfA[cg], acc[rg][cg], 0, 0, 0);
            }
            if (ke + 2 < 8) {
                #pragma unroll
                for (int cg = 0; cg < 2; ++cg)
                    bfA[cg] = *(const short8*)(bsb + (cg * 8 + ke + 2) * 512 + lane * 8);
            }
            #pragma unroll
            for (int cg = 0; cg < 2; ++cg)
                #pragma unroll
                for (int rg = 0; rg < 4; ++rg)
                    acc[rg][cg] = __builtin_amdgcn_mfma_f32_16x16x32_bf16(
                        a[rg][ko], bfB[cg], acc[rg][cg], 0, 0, 0);
            if (ko + 2 < 8) {
                #pragma unroll
                for (int cg = 0; cg < 2; ++cg)
                    bfB[cg] = *(const short8*)(bsb + (cg * 8 + ko + 2) * 512 + lane * 8);
            }
        }
    };

    // --- ct = 0, peeled: overlap A prologue with B0 DMA ---
    stage1(0, ybase, 0); stage1(0, ybase, 1);
    loadA(0); loadA(1);
    __syncthreads();         // drains B0 DMA (+ the early A loads)
    stage1(1, ybase + 8192, 0); stage1(1, ybase + 8192, 1);  // prefetch ct=1
    loadA(2); loadA(3); loadA(4); loadA(5); loadA(6); loadA(7);
    compute(0, 0);
    ybase += 8192;

    // --- cts 1..15: steady state; fold of ct-1 happens inside compute ---
    #pragma unroll 1
    for (int ct = 1; ct < 16; ++ct) {
        const int buf = ct & 1;
        __syncthreads();           // drains this ct's B DMA (issued a ct ago)
        if (ct < 15)
            stage1(buf ^ 1, ybase + 8192, 0), stage1(buf ^ 1, ybase + 8192, 1);
        compute(buf, 1);
        ybase += 8192;  // loop-carried: blocks cross-ct hoisting
    }
    fold();  // final ct's acc

    // Single epilogue: quad-lane reduce, eval C twice (quasiconcavity),
    // fire-and-forget atomicMin (no read guard -- R3 post-mortem).
    #pragma unroll
    for (int rg = 0; rg < 4; ++rg) {
        #pragma unroll
        for (int r = 0; r < 4; ++r) {
            float mn = mn4[rg][r];
            float mx = mx4[rg][r];
            #pragma unroll
            for (int mofs = 1; mofs < 16; mofs <<= 1) {
                mn = fminf(mn, __shfl_xor(mn, mofs, 64));
                mx = fmaxf(mx, __shfl_xor(mx, mofs, 64));
            }
            if (lm == 0) {
                float cmin = fminf(c_of_m(mn), c_of_m(mx));
                int row = rowStart + w * 64 + rg * 16 + lq * 4 + r;
                atomicMinFloat(&out[row], cmin);
            }
        }
    }
}

extern "C" void kernel_launch(void* const* d_in, const int* in_sizes, int n_in,
                              void* d_out, int out_size, void* d_ws, size_t ws_size,
                              hipStream_t stream) {
    const float* Ex = (const float*)d_in[0];
    const float* Ey = (const float*)d_in[1];
    float* out = (float*)d_out;
    u16* Xs = (u16*)d_ws;                // 4 MB, panel layout
    u16* Ys = Xs + (size_t)NROWS * DIM;  // 4 MB, panel layout

    void* args[] = {(void*)&Ex, (void*)&Ey, (void*)&Xs, (void*)&Ys, (void*)&out};
    hipLaunchCooperativeKernel((const void*)fused_kernel, dim3(256), dim3(512),
                               args, 0, stream);
}

// Round 13
// 93.851 us; speedup vs baseline: 1.5642x; 1.5642x over previous
//
#include <hip/hip_runtime.h>
#include <hip/hip_bf16.h>

typedef unsigned short u16;
typedef __attribute__((ext_vector_type(8))) short short8;
typedef __attribute__((ext_vector_type(4))) float floatx4;

#define NROWS 8192
#define DIM 256

__device__ __forceinline__ void atomicMinFloat(float* addr, float val) {
    if (val >= 0.0f) {
        atomicMin((int*)addr, __float_as_int(val));
    } else {
        atomicMax((unsigned int*)addr, __float_as_uint(val));
    }
}

__device__ __forceinline__ u16 f32_to_bf16_rne(float x) {
    unsigned int u = __float_as_uint(x);
    unsigned int r = (u + 0x7fffu + ((u >> 16) & 1u)) >> 16;
    return (u16)r;
}

// C(M) = -logp * exp(logp); quasiconcave in M => rowmin = min(C(minM), C(maxM)).
__device__ __forceinline__ float c_of_m(float m) {
    const float INV_SIG = 1.0f / 0.3f;
    const float KC = 0.28503427f;  // -ln(0.3) - 0.5*ln(2*pi)
    float z = (m - 1.0f) * INV_SIG;
    float logp = fmaf(-0.5f * z, z, KC);
    return -logp * __expf(logp);
}

// 16B async DMA global -> LDS. LDS dest is wave-uniform base + lane*16.
__device__ __forceinline__ void load16(const u16* g, u16* l) {
    __builtin_amdgcn_global_load_lds(
        (__attribute__((address_space(1))) void*)g,
        (__attribute__((address_space(3))) void*)l, 16, 0, 0);
}

// Normalize rows (L2-norm clamped at 1e-8), wave per row, float4 loads.
// BOTH X and Y are written in MFMA fragment ("panel") layout:
//   element (row r, k) -> flat[ ((p*8+kt)*64 + lq*16 + lm)*8 + j ]
//   p=r>>4, lm=r&15, kt=k>>5, lq=(k>>3)&3, j=k&7.
// A fragment load is then base + lane*16B: one coalesced dwordx4.
// Verified end-to-end R5/R11/R14/R15 (absmax 1.5e-5).
__global__ __launch_bounds__(256) void normalize_kernel(const float* __restrict__ Ex,
                                                        const float* __restrict__ Ey,
                                                        u16* __restrict__ Xs,
                                                        u16* __restrict__ Ys,
                                                        float* __restrict__ out) {
    const int t = threadIdx.x;
    const int ln = t & 63;
    const int row = blockIdx.x * 4 + (t >> 6);
    const float* src = (blockIdx.y == 0) ? Ex : Ey;
    u16* dst = (blockIdx.y == 0) ? Xs : Ys;

    float4 v = *(const float4*)(src + (size_t)row * DIM + ln * 4);
    float s = fmaf(v.x, v.x, fmaf(v.y, v.y, fmaf(v.z, v.z, v.w * v.w)));
    #pragma unroll
    for (int m = 32; m >= 1; m >>= 1) s += __shfl_xor(s, m, 64);
    float inv = 1.0f / fmaxf(sqrtf(s), 1e-8f);

    ushort4 o;
    o.x = f32_to_bf16_rne(v.x * inv);
    o.y = f32_to_bf16_rne(v.y * inv);
    o.z = f32_to_bf16_rne(v.z * inv);
    o.w = f32_to_bf16_rne(v.w * inv);

    const int p = row >> 4;
    const int lm = row & 15;
    const int kt = ln >> 3;
    const int lq = (ln >> 1) & 3;
    const int j4 = (ln & 1) * 4;
    const size_t off = ((size_t)((p * 8 + kt) * 64 + lq * 16 + lm)) * 8 + j4;
    *(ushort4*)(dst + off) = o;

    if (blockIdx.y == 0 && ln == 0) out[row] = __uint_as_float(0x7f800000u);  // +inf
}

// R29 = R8 champion restored verbatim (93.58 us). R12's cooperative fusion
// regressed to 74 us/dispatch: grid.sync()'s device-scope fences defeat the
// per-XCD L2 for phase 2's B-stream. Axis summary (all measured):
// schedules (setprio/8-phase/free-run/rotation/4-ring) null-to-negative;
// occupancy tiers flat; int8 fails 7.7e-5 tolerance; 32x32 MFMA regresses
// (2 acc chains); fusion negative. gemm ~30 us = m97-class 2-barrier
// ceiling at K=256; harness fill/reset ~58 us untouchable. Plateau.
__global__ void __launch_bounds__(512, 2)
gemm_min_kernel(const u16* __restrict__ Xs,
                const u16* __restrict__ Ys,
                float* __restrict__ out) {
    __shared__ u16 Bs[2][16 * 512];  // 2 x 16 KB

    const int tid = threadIdx.x;
    const int w = tid >> 6;      // 0..7 row-group (64 rows each)
    const int lane = tid & 63;
    const int lq = lane >> 4;
    const int lm = lane & 15;

    // XCD-aware remap (dispatch i -> XCD i&7 round-robin): XCD x gets a
    // 4 row-tile x 8 col-group region. Bijective over the 16x16 grid.
    const int i = blockIdx.x;
    const int x = i & 7;
    const int jj = i >> 3;                      // 0..31 within XCD
    const int rt = (x & 3) * 4 + (jj & 3);      // row-tile 0..15
    const int cgrp = (x >> 2) * 8 + (jj >> 2);  // col-group 0..15

    const int rowStart = rt * 512;
    const int rowPan0 = rt * 32 + w * 4;
    const u16* ybase = Ys + (size_t)cgrp * 32 * 4096;  // advances 8192 u16/ct

    // Stage one 32col x 256k B tile (16 KB = 16 x 1 KB units) via DMA.
    // 8 waves x 2 units; unit u -> (col-panel u>>3, kt u&7); LDS slot u*512
    // so fragment reads are Bs[(cg*8+kt)*512 + lane*8] (b128, conflict-free).
    auto stage1 = [&](int buf, const u16* yb, int iu) {
        const int u = w * 2 + iu;
        load16(yb + (u >> 3) * 4096 + (u & 7) * 512 + lane * 8,
               &Bs[buf][u * 512]);
    };

    short8 a[4][8];
    auto loadA = [&](int kt) {
        #pragma unroll
        for (int rg = 0; rg < 4; ++rg)
            a[rg][kt] = *(const short8*)(
                Xs + ((size_t)(rowPan0 + rg) * 8 + kt) * 512 + lane * 8);
    };

    floatx4 mn4[4], mx4[4];
    #pragma unroll
    for (int rg = 0; rg < 4; ++rg) {
        mn4[rg] = (floatx4){3.4e38f, 3.4e38f, 3.4e38f, 3.4e38f};
        mx4[rg] = (floatx4){-3.4e38f, -3.4e38f, -3.4e38f, -3.4e38f};
    }

    floatx4 acc[4][2];
    const floatx4 FZ = (floatx4){0.0f, 0.0f, 0.0f, 0.0f};

    auto fold = [&]() {
        #pragma unroll
        for (int rg = 0; rg < 4; ++rg)
            #pragma unroll
            for (int cg = 0; cg < 2; ++cg)
                #pragma unroll
                for (int r = 0; r < 4; ++r) {
                    float m = acc[rg][cg][r];
                    mn4[rg][r] = fminf(mn4[rg][r], m);
                    mx4[rg][r] = fmaxf(mx4[rg][r], m);
                }
    };

    // Software-pipelined compute: bfA/bfB alternate, next kt's 2 B-frags
    // issue BEFORE the current kt's 8 MFMAs (counted lgkmcnt covers the
    // latency). dofold=1 folds the PREVIOUS ct's acc right after the first
    // 4 reads are issued -- VALU work inside the LDS-latency window.
    auto compute = [&](int buf, int dofold) {
        const u16* bsb = &Bs[buf][0];
        short8 bfA[2], bfB[2];
        #pragma unroll
        for (int cg = 0; cg < 2; ++cg)
            bfA[cg] = *(const short8*)(bsb + (cg * 8 + 0) * 512 + lane * 8);
        #pragma unroll
        for (int cg = 0; cg < 2; ++cg)
            bfB[cg] = *(const short8*)(bsb + (cg * 8 + 1) * 512 + lane * 8);
        if (dofold) fold();
        #pragma unroll
        for (int k2 = 0; k2 < 4; ++k2) {
            const int ke = 2 * k2;      // even kt, uses bfA
            const int ko = ke + 1;      // odd kt, uses bfB
            if (ke == 0) {
                #pragma unroll
                for (int cg = 0; cg < 2; ++cg)
                    #pragma unroll
                    for (int rg = 0; rg < 4; ++rg)
                        acc[rg][cg] = __builtin_amdgcn_mfma_f32_16x16x32_bf16(
                            a[rg][0], bfA[cg], FZ, 0, 0, 0);
            } else {
                #pragma unroll
                for (int cg = 0; cg < 2; ++cg)
                    #pragma unroll
                    for (int rg = 0; rg < 4; ++rg)
                        acc[rg][cg] = __builtin_amdgcn_mfma_f32_16x16x32_bf16(
                            a[rg][ke], bfA[cg], acc[rg][cg], 0, 0, 0);
            }
            if (ke + 2 < 8) {
                #pragma unroll
                for (int cg = 0; cg < 2; ++cg)
                    bfA[cg] = *(const short8*)(bsb + (cg * 8 + ke + 2) * 512 + lane * 8);
            }
            #pragma unroll
            for (int cg = 0; cg < 2; ++cg)
                #pragma unroll
                for (int rg = 0; rg < 4; ++rg)
                    acc[rg][cg] = __builtin_amdgcn_mfma_f32_16x16x32_bf16(
                        a[rg][ko], bfB[cg], acc[rg][cg], 0, 0, 0);
            if (ko + 2 < 8) {
                #pragma unroll
                for (int cg = 0; cg < 2; ++cg)
                    bfB[cg] = *(const short8*)(bsb + (cg * 8 + ko + 2) * 512 + lane * 8);
            }
        }
    };

    // --- ct = 0, peeled: overlap A prologue with B0 DMA ---
    stage1(0, ybase, 0); stage1(0, ybase, 1);
    loadA(0); loadA(1);
    __syncthreads();         // drains B0 DMA (+ the early A loads)
    stage1(1, ybase + 8192, 0); stage1(1, ybase + 8192, 1);  // prefetch ct=1
    loadA(2); loadA(3); loadA(4); loadA(5); loadA(6); loadA(7);
    compute(0, 0);
    ybase += 8192;

    // --- cts 1..15: steady state; fold of ct-1 happens inside compute ---
    #pragma unroll 1
    for (int ct = 1; ct < 16; ++ct) {
        const int buf = ct & 1;
        __syncthreads();           // drains this ct's B DMA (issued a ct ago)
        if (ct < 15)
            stage1(buf ^ 1, ybase + 8192, 0), stage1(buf ^ 1, ybase + 8192, 1);
        compute(buf, 1);
        ybase += 8192;  // loop-carried: blocks cross-ct hoisting
    }
    fold();  // final ct's acc

    // Single epilogue: quad-lane reduce, eval C twice (quasiconcavity),
    // fire-and-forget atomicMin (no read guard -- R3 post-mortem).
    #pragma unroll
    for (int rg = 0; rg < 4; ++rg) {
        #pragma unroll
        for (int r = 0; r < 4; ++r) {
            float mn = mn4[rg][r];
            float mx = mx4[rg][r];
            #pragma unroll
            for (int mofs = 1; mofs < 16; mofs <<= 1) {
                mn = fminf(mn, __shfl_xor(mn, mofs, 64));
                mx = fmaxf(mx, __shfl_xor(mx, mofs, 64));
            }
            if (lm == 0) {
                float cmin = fminf(c_of_m(mn), c_of_m(mx));
                int row = rowStart + w * 64 + rg * 16 + lq * 4 + r;
                atomicMinFloat(&out[row], cmin);
            }
        }
    }
}

extern "C" void kernel_launch(void* const* d_in, const int* in_sizes, int n_in,
                              void* d_out, int out_size, void* d_ws, size_t ws_size,
                              hipStream_t stream) {
    const float* Ex = (const float*)d_in[0];
    const float* Ey = (const float*)d_in[1];
    float* out = (float*)d_out;
    u16* Xs = (u16*)d_ws;                // 4 MB, panel layout
    u16* Ys = Xs + (size_t)NROWS * DIM;  // 4 MB, panel layout

    hipLaunchKernelGGL(normalize_kernel, dim3(NROWS / 4, 2), dim3(256), 0, stream,
                       Ex, Ey, Xs, Ys, out);
    hipLaunchKernelGGL(gemm_min_kernel, dim3(16 * 16), dim3(512), 0, stream,
                       Xs, Ys, out);
}